// Round 5
// baseline (1139.355 us; speedup 1.0000x reference)
//
#include <hip/hip_runtime.h>

// ---------------------------------------------------------------------------
// SRU LM as ONE persistent cooperative-style mega-kernel (256 blocks x 1024).
// emb-gather -> SRU(512->1024,k4) -> 4x SRU(1024,k3) -> SRU(1024->512,k4)
//   -> logits = h @ emb^T + bias
// L=128 B=32 E=512 D=1024 V=32000 MID=4
// All phases separated by a manual device-scope grid barrier (all 256 blocks
// are co-resident: 128 KiB LDS => 1 block/CU, grid == CU count).
// GEMM: 256x256 tile, 16 waves, BK=64 dbuf, counted vmcnt, slot-XOR swizzle.
// U scratch lives in d_out (overwritten at the end by the logits GEMM).
// ---------------------------------------------------------------------------

typedef __attribute__((ext_vector_type(8))) __bf16 bf16x8;
typedef __attribute__((ext_vector_type(4))) float f32x4;
typedef __attribute__((ext_vector_type(4))) float float4v;
typedef __attribute__((ext_vector_type(4))) unsigned short u16x4;

__device__ __forceinline__ unsigned short f2bf(float f) {
  unsigned int u = __builtin_bit_cast(unsigned int, f);
  u += 0x7fffu + ((u >> 16) & 1u);          // RNE
  return (unsigned short)(u >> 16);
}
__device__ __forceinline__ float bf2f(unsigned short v) {
  unsigned int u = ((unsigned int)v) << 16;
  return __builtin_bit_cast(float, u);
}

#define GLDS16(SRC, DST)                                                      \
  __builtin_amdgcn_global_load_lds(                                           \
      (__attribute__((address_space(1))) void*)(SRC),                         \
      (__attribute__((address_space(3))) void*)(DST), 16, 0, 0)

// --------------------------- grid barrier ----------------------------------
// Sense-free generation barrier. cnt/gen zeroed by hipMemsetAsync each call.
// Release: __syncthreads drains each thread's vmem (compiler semantics), then
// tid0's __threadfence (agent fence: wbl2) publishes the XCD's writes.
// Acquire: tid0's post-wait __threadfence invalidates L1/L2 before the block
// proceeds past the final __syncthreads.
__device__ __forceinline__ void grid_sync(unsigned* cnt, unsigned* gen) {
  __syncthreads();
  if (threadIdx.x == 0) {
    __threadfence();
    const unsigned g =
        __hip_atomic_load(gen, __ATOMIC_RELAXED, __HIP_MEMORY_SCOPE_AGENT);
    if (atomicAdd(cnt, 1u) == gridDim.x - 1) {
      __hip_atomic_store(cnt, 0u, __ATOMIC_RELAXED, __HIP_MEMORY_SCOPE_AGENT);
      __hip_atomic_fetch_add(gen, 1u, __ATOMIC_RELEASE,
                             __HIP_MEMORY_SCOPE_AGENT);
    } else {
      while (__hip_atomic_load(gen, __ATOMIC_RELAXED,
                               __HIP_MEMORY_SCOPE_AGENT) == g)
        __builtin_amdgcn_s_sleep(2);
    }
    __threadfence();
  }
  __syncthreads();
}

// --------------------------- GEMM phase ------------------------------------
// C[m][n] = sum_k A[m][k]*B[n][k] (+bias).  A:(M,K) bf16, B:(N,K) bf16,
// C:(M,N) fp32.  Persistent tile loop: t = bid, bid+256, ...
// colmajor mapping (logits): m0=(t&15)*256, n0=(t>>4)*256  (A-panel locality).
__device__ __forceinline__ void gemm_tiles(
    const unsigned short* __restrict__ A, const unsigned short* __restrict__ B,
    float* __restrict__ C, const float* __restrict__ bias, int N, int K,
    int total, int tiles_n, bool colmajor, unsigned short* __restrict__ sm,
    int bid, int tid) {
  const int lane = tid & 63;
  const int w    = tid >> 6;            // 0..15
  const int wm = w >> 2, wn = w & 3;    // 4x4 wave grid, 64x64 out per wave
  const int srow  = lane >> 3;
  const int sslot = (lane & 7) ^ srow;
  const int fr = lane & 15;
  const int lg = lane >> 4;
  const int NT = K >> 6;

  unsigned short* smA0 = sm;
  unsigned short* smB0 = sm + 16384;
  unsigned short* smA1 = sm + 32768;
  unsigned short* smB1 = sm + 49152;

#define STAGE(G, row0, k0v, dstbase)                                          \
  {                                                                           \
    _Pragma("unroll") for (int j = 0; j < 2; ++j) {                           \
      const unsigned short* src = (G) +                                       \
          (size_t)((row0) + j * 128 + w * 8 + srow) * K + (k0v) + sslot * 8;  \
      GLDS16(src, (dstbase) + j * 8192 + w * 512);                            \
    }                                                                         \
  }

  for (int t = bid; t < total; t += 256) {
    int m0, n0;
    if (colmajor) { m0 = (t & 15) << 8; n0 = (t >> 4) << 8; }
    else          { m0 = (t / tiles_n) << 8; n0 = (t % tiles_n) << 8; }

    f32x4 acc[4][4] = {};

    STAGE(A, m0, 0, smA0); STAGE(B, n0, 0, smB0);
    STAGE(A, m0, 64, smA1); STAGE(B, n0, 64, smB1);
    asm volatile("s_waitcnt vmcnt(4)" ::: "memory");   // tile0 landed
    __builtin_amdgcn_s_barrier();

    int cur = 0;
    for (int kt = 0; kt < NT; ++kt) {
      const unsigned short* As = cur ? smA1 : smA0;
      const unsigned short* Bs = cur ? smB1 : smB0;
      bf16x8 bfr[2][4];
#pragma unroll
      for (int q = 0; q < 4; ++q) {
        if (q == 0) {
#pragma unroll
          for (int kk = 0; kk < 2; ++kk)
#pragma unroll
            for (int n = 0; n < 4; ++n) {
              const int row  = wn * 64 + n * 16 + fr;
              const int slot = (kk * 4 + lg) ^ (row & 7);
              bfr[kk][n] = *(const bf16x8*)&Bs[row * 64 + slot * 8];
            }
        }
        bf16x8 afr[2];
#pragma unroll
        for (int kk = 0; kk < 2; ++kk) {
          const int row  = wm * 64 + q * 16 + fr;
          const int slot = (kk * 4 + lg) ^ (row & 7);
          afr[kk] = *(const bf16x8*)&As[row * 64 + slot * 8];
        }
        __builtin_amdgcn_s_barrier();
        asm volatile("s_waitcnt lgkmcnt(0)" ::: "memory");
        __builtin_amdgcn_sched_barrier(0);
        __builtin_amdgcn_s_setprio(1);
#pragma unroll
        for (int kk = 0; kk < 2; ++kk)
#pragma unroll
          for (int n = 0; n < 4; ++n)
            acc[q][n] = __builtin_amdgcn_mfma_f32_16x16x32_bf16(
                afr[kk], bfr[kk][n], acc[q][n], 0, 0, 0);
        __builtin_amdgcn_s_setprio(0);
        __builtin_amdgcn_s_barrier();
      }
      __builtin_amdgcn_sched_barrier(0);
      if (kt + 2 < NT) {
        const int k2 = (kt + 2) << 6;
        unsigned short* dA = cur ? smA1 : smA0;
        unsigned short* dB = cur ? smB1 : smB0;
        STAGE(A, m0, k2, dA); STAGE(B, n0, k2, dB);
        asm volatile("s_waitcnt vmcnt(4)" ::: "memory");
      } else {
        asm volatile("s_waitcnt vmcnt(0)" ::: "memory");
      }
      __builtin_amdgcn_s_barrier();
      __builtin_amdgcn_sched_barrier(0);
      cur ^= 1;
    }

    // epilogue: C write (+bias)
#pragma unroll
    for (int n = 0; n < 4; ++n) {
      const int col = n0 + wn * 64 + n * 16 + fr;
      const float bv = bias ? bias[col] : 0.0f;
#pragma unroll
      for (int m = 0; m < 4; ++m) {
        const int row = m0 + wm * 64 + m * 16 + lg * 4;
#pragma unroll
        for (int r = 0; r < 4; ++r)
          C[(size_t)(row + r) * N + col] = acc[m][n][r] + bv;
      }
    }
  }
#undef STAGE
}

// --------------------------- scan phase ------------------------------------
// 4-deep software-pipelined SRU scan.  Active waves spread across blocks:
// wave-quota q = ceil(nwave/256), g = bid*q + (tid>>6), chain = g*64+lane.
template <bool K4, int NOUT>
__device__ __forceinline__ void scan_phase(
    const float* __restrict__ U, const float* __restrict__ bias,
    const float* __restrict__ c0, const unsigned short* __restrict__ hin,
    unsigned short* __restrict__ hout, int bid, int tid) {
  const int nwave = (NOUT * 32) >> 6;
  const int q = (nwave + 255) >> 8;
  const int wv = tid >> 6;
  if (wv >= q) return;
  const int g = bid * q + wv;
  if (g >= nwave) return;
  const int idx = g * 64 + (tid & 63);

  const int b = idx / NOUT;
  const int d = idx - b * NOUT;
  const float biasf = bias[d];
  const float biasr = bias[NOUT + d];
  float c = c0[idx];
  const int rowlen = (K4 ? 4 : 3) * NOUT;
  const float* Up = U + (size_t)b * rowlen + d;
  const size_t lstride = (size_t)32 * rowlen;
  const unsigned short* hp = hin + (size_t)b * NOUT + d;
  unsigned short* op = hout + (size_t)b * NOUT + d;
  const size_t hstride = (size_t)32 * NOUT;

  float xt0, fr0, rr0, hw0, xt1, fr1, rr1, hw1;
  float xt2, fr2, rr2, hw2, xt3, fr3, rr3, hw3;

#define SRU_LOAD(S)                                                           \
  do {                                                                        \
    xt##S = Up[0];                                                            \
    fr##S = Up[NOUT];                                                         \
    rr##S = Up[2 * NOUT];                                                     \
    hw##S = K4 ? Up[3 * NOUT] : bf2f(*hp);                                    \
    Up += lstride;                                                            \
    hp += hstride;                                                            \
  } while (0)

#define SRU_STEP(S)                                                           \
  do {                                                                        \
    const float f = 1.0f / (1.0f + __expf(-(fr##S + biasf)));                 \
    const float r = 1.0f / (1.0f + __expf(-(rr##S + biasr)));                 \
    c = f * c + (1.0f - f) * xt##S;                                           \
    const float e2 = __expf(2.0f * c);                                        \
    const float g2 = 1.0f - 2.0f / (e2 + 1.0f);                               \
    *op = f2bf(r * g2 + (1.0f - r) * hw##S);                                  \
    op += hstride;                                                            \
  } while (0)

  SRU_LOAD(0); SRU_LOAD(1); SRU_LOAD(2); SRU_LOAD(3);
  for (int l = 0; l < 124; l += 4) {
    SRU_STEP(0); SRU_LOAD(0);
    SRU_STEP(1); SRU_LOAD(1);
    SRU_STEP(2); SRU_LOAD(2);
    SRU_STEP(3); SRU_LOAD(3);
  }
  SRU_STEP(0); SRU_STEP(1); SRU_STEP(2); SRU_STEP(3);
#undef SRU_LOAD
#undef SRU_STEP
}

// --------------------------- mega kernel -----------------------------------
__global__ __launch_bounds__(1024, 4)
void mega(const int* __restrict__ x, const float* __restrict__ c1,
          const float* __restrict__ c2, const float* __restrict__ c3,
          const float* __restrict__ emb, const float* __restrict__ obias,
          const float* __restrict__ W1, const float* __restrict__ b1,
          const float* __restrict__ W2, const float* __restrict__ b2,
          const float* __restrict__ W3, const float* __restrict__ b3,
          unsigned short* __restrict__ embbf, unsigned short* __restrict__ hbfA,
          unsigned short* __restrict__ hbfB, unsigned short* __restrict__ W1t,
          unsigned short* __restrict__ W2t, unsigned short* __restrict__ W3t,
          float* __restrict__ U, float* __restrict__ out,
          unsigned* cnt, unsigned* gen) {
  __shared__ __align__(16) unsigned char smem[131072];
  unsigned short* sm16 = (unsigned short*)smem;
  const int bid = blockIdx.x;
  const int tid = threadIdx.x;
  const int gtid = bid * 1024 + tid;

  // ---------------- phase 0: prep (cvt, gather, transposes) ----------------
  for (int i = gtid; i < 4096000; i += 262144) {       // emb f32 -> bf16, x4
    const float4v v = ((const float4v*)emb)[i];
    u16x4 o;
    o.x = f2bf(v.x); o.y = f2bf(v.y); o.z = f2bf(v.z); o.w = f2bf(v.w);
    ((u16x4*)embbf)[i] = o;
  }
  for (int i = gtid; i < 2097152; i += 262144) {       // token gather
    const int row = i >> 9, e = i & 511;
    const int tok = x[row];
    hbfA[i] = f2bf(emb[((size_t)tok << 9) + e]);
  }
  {                                                    // 16384 32x32 transposes
    const int grp = tid >> 8;                          // 4 tiles per block/iter
    const int t2 = tid & 255;
    const int tx = t2 & 31, ty = t2 >> 5;
    float* tile = (float*)(smem + grp * 4352);         // 32x33 f32 = 4224 B
    for (int it = 0; it < 16; ++it) {
      const int tg = (it * 256 + bid) * 4 + grp;       // 0..16383
      const float* W; unsigned short* Wt; int K, N, bx, by;
      if (tg < 2048)       { W = W1; Wt = W1t; K = 512;  N = 4096;
                             bx = tg & 127; by = tg >> 7; }
      else if (tg < 14336) { const int r = tg - 2048; const int i2 = r / 3072;
                             const int rr = r - i2 * 3072;
                             W = W2 + (size_t)i2 * 3145728;
                             Wt = W2t + (size_t)i2 * 3145728;
                             K = 1024; N = 3072; bx = rr % 96; by = rr / 96; }
      else                 { const int r = tg - 14336; W = W3; Wt = W3t;
                             K = 1024; N = 2048; bx = r & 63; by = r >> 6; }
      const int n0 = bx * 32, k0 = by * 32;
#pragma unroll
      for (int i2 = 0; i2 < 32; i2 += 8)
        tile[(ty + i2) * 33 + tx] = W[(size_t)(k0 + ty + i2) * N + n0 + tx];
      __syncthreads();
#pragma unroll
      for (int i2 = 0; i2 < 32; i2 += 8)
        Wt[(size_t)(n0 + ty + i2) * K + k0 + tx] = f2bf(tile[tx * 33 + ty + i2]);
      __syncthreads();
    }
  }
  grid_sync(cnt, gen);

  // ---------------- layer 1: (512 -> 1024, k=4) ----------------------------
  gemm_tiles(hbfA, W1t, U, nullptr, 4096, 512, 256, 16, false, sm16, bid, tid);
  grid_sync(cnt, gen);
  scan_phase<true, 1024>(U, b1, c1, hbfB, hbfB, bid, tid);
  grid_sync(cnt, gen);

  // ---------------- mid layers: 4x (1024 -> 1024, k=3) ---------------------
  const unsigned short* hin = hbfB;
  unsigned short* hout = hbfA;
  for (int i = 0; i < 4; ++i) {
    gemm_tiles(hin, W2t + (size_t)i * 3145728, U, nullptr, 3072, 1024, 192, 12,
               false, sm16, bid, tid);
    grid_sync(cnt, gen);
    scan_phase<false, 1024>(U, b2 + i * 2048, c2 + (size_t)i * 32768, hin, hout,
                            bid, tid);
    grid_sync(cnt, gen);
    const unsigned short* tswap = hin; hin = hout; hout = (unsigned short*)tswap;
  }

  // ---------------- final SRU: (1024 -> 512, k=4) --------------------------
  gemm_tiles(hin, W3t, U, nullptr, 2048, 1024, 128, 8, false, sm16, bid, tid);
  grid_sync(cnt, gen);
  scan_phase<true, 512>(U, b3, c3, hout, hout, bid, tid);  // writes hout
  grid_sync(cnt, gen);

  // ---------------- logits: (4096 x 32000) ---------------------------------
  gemm_tiles(hout, embbf, out, obias, 32000, 512, 2000, 125, true, sm16, bid,
             tid);
}

extern "C" void kernel_launch(void* const* d_in, const int* in_sizes, int n_in,
                              void* d_out, int out_size, void* d_ws, size_t ws_size,
                              hipStream_t stream) {
  (void)in_sizes; (void)n_in; (void)out_size; (void)ws_size;
  const int*   x     = (const int*)d_in[0];
  const float* c1    = (const float*)d_in[1];
  const float* c2    = (const float*)d_in[2];
  const float* c3    = (const float*)d_in[3];
  const float* emb   = (const float*)d_in[4];
  const float* obias = (const float*)d_in[5];
  const float* W1    = (const float*)d_in[6];
  const float* b1    = (const float*)d_in[7];
  const float* W2    = (const float*)d_in[8];
  const float* b2    = (const float*)d_in[9];
  const float* W3    = (const float*)d_in[10];
  const float* b3    = (const float*)d_in[11];

  char* ws = (char*)d_ws;
  unsigned short* hbfA  = (unsigned short*)ws;                  //  8,388,608 B
  unsigned short* hbfB  = (unsigned short*)(ws + 8388608);      //  8,388,608 B
  unsigned short* embbf = (unsigned short*)(ws + 16777216);     // 32,768,000 B
  unsigned short* W1t   = (unsigned short*)(ws + 49545216);     //  4,194,304 B
  unsigned short* W2t   = (unsigned short*)(ws + 53739520);     // 25,165,824 B
  unsigned short* W3t   = (unsigned short*)(ws + 78905344);     //  4,194,304 B
  unsigned* bar = (unsigned*)(ws + 104857600);                  // cnt, gen
  float* U = (float*)d_out;   // 64 MB scratch; overwritten by logits at end.

  hipMemsetAsync(bar, 0, 8, stream);   // cnt=0, gen=0 (ws is poisoned 0xAA)
  mega<<<256, 1024, 0, stream>>>(x, c1, c2, c3, emb, obias, W1, b1, W2, b2,
                                 W3, b3, embbf, hbfA, hbfB, W1t, W2t, W3t,
                                 U, (float*)d_out, bar, bar + 1);
}